// Round 11
// baseline (309.254 us; speedup 1.0000x reference)
//
#include <hip/hip_runtime.h>

#define RAYS 65536
#define NS   192

using f4 = float __attribute__((ext_vector_type(4)));   // clang vector: NT-builtin compatible

__device__ __forceinline__ int   f2i(float x){ return __builtin_bit_cast(int, x); }
__device__ __forceinline__ float i2f(int x)  { return __builtin_bit_cast(float, x); }

// v_mov_b32_dpp with old=0, bound_ctrl:0
template<int CTRL, int ROWMASK>
__device__ __forceinline__ float dpp0(float x){
    return i2f(__builtin_amdgcn_update_dpp(0, f2i(x), CTRL, ROWMASK, 0xF, true));
}
template<int OFF>
__device__ __forceinline__ float swz(float x){
    return i2f(__builtin_amdgcn_ds_swizzle(f2i(x), OFF));
}

// partner at sub-lane XOR distance JL; DPP everywhere except xor16/31.
template<int JL>
__device__ __forceinline__ float partner(float x){
    if      constexpr (JL == 1)  return dpp0<0xB1,  0xF>(x);                    // quad_perm xor1
    else if constexpr (JL == 2)  return dpp0<0x4E,  0xF>(x);                    // quad_perm xor2
    else if constexpr (JL == 3)  return dpp0<0x1B,  0xF>(x);                    // quad_perm xor3
    else if constexpr (JL == 4)  return dpp0<0x141, 0xF>(dpp0<0x1B, 0xF>(x));   // xor7(xor3)
    else if constexpr (JL == 7)  return dpp0<0x141, 0xF>(x);                    // row_half_mirror
    else if constexpr (JL == 8)  return dpp0<0x128, 0xF>(x);                    // row_ror:8
    else if constexpr (JL == 15) return dpp0<0x140, 0xF>(x);                    // row_mirror
    else if constexpr (JL == 16) return swz<0x401F>(x);                         // xor16
    else                         return swz<0x7C1F>(x);                         // xor31
}

__device__ __forceinline__ void ce(float &a, float &b){
    float mn = fminf(a, b), mx = fmaxf(a, b);
    a = mn; b = mx;
}

template<int JL>
__device__ __forceinline__ void xphase(float v[8], bool lower){
    #pragma unroll
    for (int r = 0; r < 8; ++r){
        float p = partner<JL>(v[r]);
        v[r] = ((v[r] < p) == lower) ? v[r] : p;
    }
}

template<int JL>
__device__ __forceinline__ void xmirror(float v[8], bool lower){
    #pragma unroll
    for (int r = 0; r < 4; ++r){
        float pa = partner<JL>(v[7 - r]);
        float pb = partner<JL>(v[r]);
        v[r]     = ((v[r]     < pa) == lower) ? v[r]     : pa;
        v[7 - r] = ((v[7 - r] < pb) == lower) ? v[7 - r] : pb;
    }
}

__device__ __forceinline__ void rmerge(float v[8]){
    ce(v[0],v[4]); ce(v[1],v[5]); ce(v[2],v[6]); ce(v[3],v[7]);
    ce(v[0],v[2]); ce(v[1],v[3]); ce(v[4],v[6]); ce(v[5],v[7]);
    ce(v[0],v[1]); ce(v[2],v[3]); ce(v[4],v[5]); ce(v[6],v[7]);
}

__device__ __forceinline__ void sort8(float v[8]){
    ce(v[0],v[1]); ce(v[2],v[3]); ce(v[4],v[5]); ce(v[6],v[7]);
    ce(v[0],v[2]); ce(v[1],v[3]); ce(v[4],v[6]); ce(v[5],v[7]);
    ce(v[1],v[2]); ce(v[5],v[6]);
    ce(v[0],v[4]); ce(v[1],v[5]); ce(v[2],v[6]); ce(v[3],v[7]);
    ce(v[2],v[4]); ce(v[3],v[5]);
    ce(v[1],v[2]); ce(v[3],v[4]); ce(v[5],v[6]);
}

// 32-lane butterfly sum, masks {1,2,7,8,16}
__device__ __forceinline__ float halfsum(float a){
    a += dpp0<0xB1,  0xF>(a);   // xor1
    a += dpp0<0x4E,  0xF>(a);   // xor2
    a += dpp0<0x141, 0xF>(a);   // xor7
    a += dpp0<0x128, 0xF>(a);   // xor8
    a += swz<0x401F>(a);        // xor16
    return a;
}

__global__ __launch_bounds__(256) void nerf_integrate(
    const float* __restrict__ t,
    const float* __restrict__ sigma,
    const float* __restrict__ c,
    float* __restrict__ out)
{
    const int tid  = threadIdx.x;
    const int lane = tid & 63;
    const int sl   = tid & 31;

    // XCD-aware swizzle: 8192 wgs, 8 XCDs -> each XCD walks a contiguous
    // 1024-block chunk (contiguous 32MB slice of each stream per L2).
    const int bid = blockIdx.x;
    const int wg  = (bid & 7) * 1024 + (bid >> 3);
    const int ray = wg * 8 + (tid >> 5);

    const bool lo1  = (sl & 1)  == 0;
    const bool lo2  = (sl & 2)  == 0;
    const bool lo4  = (sl & 4)  == 0;
    const bool lo8  = (sl & 8)  == 0;
    const bool lo16 = (sl & 16) == 0;

    const bool act = (sl < 24);
    const int  sls = act ? sl : 0;

    // ---- t: coalesced, NON-TEMPORAL (no L3 allocate) ----
    const float* trow = t + (size_t)ray * 193;
    float v[8];
    #pragma unroll
    for (int j = 0; j < 6; ++j) v[j] = __builtin_nontemporal_load(trow + 32 * j + sl);
    float t192 = __builtin_nontemporal_load(trow + 192);
    v[6] = (sl == 0) ? t192 : 1e30f;
    v[7] = 1e30f;

    // ---- sigma & c: NON-TEMPORAL f4 streams ----
    const f4* srow4 = reinterpret_cast<const f4*>(sigma + (size_t)ray * NS + 8 * sls);
    f4 s0 = __builtin_nontemporal_load(srow4);
    f4 s1 = __builtin_nontemporal_load(srow4 + 1);

    const f4* crow4 = reinterpret_cast<const f4*>(c + (size_t)ray * (NS * 3) + 24 * sls);
    f4 c0 = __builtin_nontemporal_load(crow4);
    f4 c1 = __builtin_nontemporal_load(crow4 + 1);
    f4 c2 = __builtin_nontemporal_load(crow4 + 2);
    f4 c3 = __builtin_nontemporal_load(crow4 + 3);
    f4 c4 = __builtin_nontemporal_load(crow4 + 4);
    f4 c5 = __builtin_nontemporal_load(crow4 + 5);

    // ==== mirror-normalized bitonic sort of 256: bits [2:0]=r, [7:3]=sl ====
    sort8(v);
    xmirror<1>(v, lo1);
    rmerge(v);
    xmirror<3>(v, lo2);
    xphase<1>(v, lo1);
    rmerge(v);
    xmirror<7>(v, lo4);
    xphase<2>(v, lo2);
    xphase<1>(v, lo1);
    rmerge(v);
    xmirror<15>(v, lo8);
    xphase<4>(v, lo4);
    xphase<2>(v, lo2);
    xphase<1>(v, lo1);
    rmerge(v);
    xmirror<31>(v, lo16);
    xphase<8>(v, lo8);
    xphase<4>(v, lo4);
    xphase<2>(v, lo2);
    xphase<1>(v, lo1);
    rmerge(v);

    // ---- neighbor for r=7 ----
    float nxt = __shfl(v[0], lane + 1, 64);

    // ---- sdt ----
    float sg8[8] = { s0.x, s0.y, s0.z, s0.w, s1.x, s1.y, s1.z, s1.w };
    float sdt[8];
    #pragma unroll
    for (int r = 0; r < 8; ++r){
        float tn = (r < 7) ? v[r + 1] : nxt;
        sdt[r] = act ? sg8[r] * (tn - v[r]) : 0.0f;
    }

    // ---- prefix sum: in-lane inclusive over 8, then per-half DPP scan ----
    float pre[8];
    float run = 0.0f;
    #pragma unroll
    for (int r = 0; r < 8; ++r){ run += sdt[r]; pre[r] = run; }
    float x = run;
    x += dpp0<0x111, 0xF>(x);   // row_shr:1
    x += dpp0<0x112, 0xF>(x);   // row_shr:2
    x += dpp0<0x114, 0xF>(x);   // row_shr:4
    x += dpp0<0x118, 0xF>(x);   // row_shr:8
    x += dpp0<0x142, 0xA>(x);   // row_bcast:15 -> rows 1,3
    float laneExcl = x - run;

    // ---- wi via telescoped exponentials ----
    float wi[8];
    float prev = __expf(-laneExcl);
    #pragma unroll
    for (int r = 0; r < 8; ++r){
        float e = __expf(-(laneExcl + pre[r]));
        wi[r] = prev - e;
        prev = e;
    }
    if (act){
        f4* wrow4 = reinterpret_cast<f4*>(out + (size_t)RAYS * 3 + (size_t)ray * NS + 8 * sl);
        f4 w0; w0.x = wi[0]; w0.y = wi[1]; w0.z = wi[2]; w0.w = wi[3];
        f4 w1; w1.x = wi[4]; w1.y = wi[5]; w1.z = wi[6]; w1.w = wi[7];
        __builtin_nontemporal_store(w0, wrow4);
        __builtin_nontemporal_store(w1, wrow4 + 1);
    }

    // ---- rgb, per-half reduce ----
    float cf[24] = { c0.x,c0.y,c0.z,c0.w, c1.x,c1.y,c1.z,c1.w,
                     c2.x,c2.y,c2.z,c2.w, c3.x,c3.y,c3.z,c3.w,
                     c4.x,c4.y,c4.z,c4.w, c5.x,c5.y,c5.z,c5.w };
    float a0 = 0.f, a1 = 0.f, a2 = 0.f;
    #pragma unroll
    for (int r = 0; r < 8; ++r){
        a0 += wi[r] * cf[3*r + 0];
        a1 += wi[r] * cf[3*r + 1];
        a2 += wi[r] * cf[3*r + 2];
    }
    a0 = halfsum(a0);
    a1 = halfsum(a1);
    a2 = halfsum(a2);
    if (sl < 3){
        float val = (sl == 0) ? a0 : ((sl == 1) ? a1 : a2);
        out[(size_t)ray * 3 + sl] = val;
    }
}

extern "C" void kernel_launch(void* const* d_in, const int* in_sizes, int n_in,
                              void* d_out, int out_size, void* d_ws, size_t ws_size,
                              hipStream_t stream) {
    const float* t     = (const float*)d_in[0];
    const float* sigma = (const float*)d_in[1];
    const float* c     = (const float*)d_in[2];
    float* out = (float*)d_out;
    nerf_integrate<<<RAYS / 8, 256, 0, stream>>>(t, sigma, c, out);
}